// Round 2
// baseline (144.278 us; speedup 1.0000x reference)
//
#include <hip/hip_runtime.h>
#include <stdint.h>

typedef unsigned long long ull;

#define NUM_CLASSES 21
#define NFG 20
#define TOPK 200
#define KPRE 256
#define CONF_TH 0.01f
#define NMS_TH 0.45f
#define VAR0 0.1f
#define VAR1 0.2f
#define NVMAX 35                 // ceil(8732/256)
#define BITS_CONF 0x3C23D70Au    // __float_as_uint(0.01f)
#define BITS_ONE1 0x3F800001u    // just above 1.0f (softmax <= 1)
// skewed LDS slot: g, g+64, g+128, g+192 land in different banks
#define BSLOT(g) ((g) + ((g) >> 6))

// Kernel 1: per-row softmax normalizers ONLY: (mx, sum). Replaces the full
// 22.35 MB probs tensor with a 2.2 MB float2 array. Sum order is the same
// sequential j=0..20 chain as the previously-passing kernel, so downstream
// scores expf(x-mx)/s are bit-identical.
__global__ __launch_bounds__(256) void rownorm_kernel(
    const float* __restrict__ conf, float2* __restrict__ norm, int P) {
    __shared__ __align__(16) float buf[256 * NUM_CLASSES];   // 21504 B
    const int t = threadIdx.x;
    const int b = blockIdx.y;
    const int p0 = blockIdx.x << 8;
    const int cnt = min(256, P - p0);
    const float* src = conf + ((size_t)b * P + p0) * NUM_CLASSES;

    if (cnt == 256) {
        const float4* s4 = (const float4*)src;   // (b*P+p0)*21 ≡ 0 mod 4 => aligned
        float4* b4 = (float4*)buf;
#pragma unroll
        for (int k = 0; k < 6; ++k) {
            int i = (k << 8) + t;
            if (i < (256 * NUM_CLASSES) / 4) b4[i] = s4[i];
        }
    } else {
        int n = cnt * NUM_CLASSES;
        for (int i = t; i < n; i += 256) buf[i] = src[i];
    }
    __syncthreads();

    if (t < cnt) {
        const float* row = buf + t * NUM_CLASSES;   // stride 21 => 2-way (free)
        float x[NUM_CLASSES];
        float mx = row[0];
        x[0] = mx;
#pragma unroll
        for (int j = 1; j < NUM_CLASSES; ++j) { x[j] = row[j]; mx = fmaxf(mx, x[j]); }
        float s = 0.f;
#pragma unroll
        for (int j = 0; j < NUM_CLASSES; ++j) s += expf(x[j] - mx);
        norm[(size_t)b * P + p0 + t] = make_float2(mx, s);   // coalesced 8B/lane
    }
}

// Kernel 2: one block per (b, fg_class). Computes its own class scores from
// conf + normalizers (bit-identical to the old probs values).
__global__ __launch_bounds__(KPRE) void nms_topk_kernel(
    const float* __restrict__ conf, const float2* __restrict__ norm,
    const float* __restrict__ loc, const float* __restrict__ prior,
    float* __restrict__ out, int B, int P) {

    __shared__ ull arr[2 * KPRE];
    __shared__ ull arr2[2 * KPRE];              // double buffer for sort LDS stages
    __shared__ int wsum[2][4];
    __shared__ int s_cnt;
    __shared__ float4 sbox[KPRE + (KPRE >> 6)]; // skewed (BSLOT): no 4-way conflict
    __shared__ float sarea[KPRE + (KPRE >> 6)];
    __shared__ ull smask[KPRE][5];              // padded stride 40B: 2-way (free)
    __shared__ ull kept_mask[4];

    const int t = threadIdx.x;
    const int lane = t & 63;
    const int wid = t >> 6;
    const ull lmask_lt = (1ULL << lane) - 1ULL;

    // XCD-aware swizzle: default dispatch round-robins blockIdx over 8 XCDs,
    // so g&7 selects the XCD. Map all 20 classes of an image to ONE XCD so
    // the 733 KB conf slab is HBM-fetched once per XCD and the 20x redundant
    // column reads hit that XCD's L2.
    const int g = blockIdx.x;
    int b, c;
    if ((B & 7) == 0) {
        int k = g >> 3;
        b = ((k / NFG) << 3) + (g & 7);
        c = k - (k / NFG) * NFG;
    } else {
        b = g / NFG;
        c = g - (g / NFG) * NFG;
    }
    const int pair = b * NFG + c;
    const float* cb = conf + ((size_t)b * P) * NUM_CLASSES + (c + 1);
    const float2* nb = norm + (size_t)b * P;

    // A: compute this class's scores into registers.
    // score = expf(x - mx) / s  — same ops/order as the verified softmax, so
    // values (and every downstream compare) are bit-identical.
    unsigned int ubits[NVMAX];
#pragma unroll
    for (int i = 0; i < NVMAX; ++i) {
        int p = (i << 8) + t;
        if (p < P) {
            float x = cb[(size_t)p * NUM_CLASSES];
            float2 ms = nb[p];
            ubits[i] = __float_as_uint(expf(x - ms.x) / ms.y);
        } else {
            ubits[i] = 0u;
        }
    }

    // B: WAVE-LOCAL binary search (no barriers, no shfl-reduce). Each wave
    // finds largest T_w with its own count >= 64 via ballot+popc (SALU).
    // Global T = min_w T_w  =>  count_global(>=T) >= 256 and T <= V256,
    // so {x >= T} is an exact superset of the global top-256.
    {
        unsigned int lo = BITS_CONF, hi = BITS_ONE1;
        while (hi - lo > 1u) {
            unsigned int mid = lo + ((hi - lo) >> 1);
            int cc = 0;
#pragma unroll
            for (int i = 0; i < NVMAX; ++i)
                cc += __popcll(__ballot(ubits[i] >= mid));
            if (cc >= KPRE / 4) lo = mid; else hi = mid;
        }
        if (lane == 0) wsum[0][wid] = (int)lo;
    }
    __syncthreads();
    unsigned int T = (unsigned int)min(min(wsum[0][0], wsum[0][1]),
                                       min(wsum[0][2], wsum[0][3]));

    // C: ballot-compaction gather (cap 512) + exact-search fallback if the
    // wave-local threshold over-collects (>512: statistically never).
    int nval;
    for (int attempt = 0;; ++attempt) {
        if (t == 0) s_cnt = 0;
        __syncthreads();
        int wtot = 0;
#pragma unroll
        for (int i = 0; i < NVMAX; ++i) {
            int p = (i << 8) + t;
            bool pred = (p < P) && (ubits[i] >= T);
            wtot += __popcll(__ballot(pred));
        }
        int wbase = 0;
        if (lane == 0) wbase = atomicAdd(&s_cnt, wtot);
        wbase = __shfl(wbase, 0);
        int run = wbase;
#pragma unroll
        for (int i = 0; i < NVMAX; ++i) {
            int p = (i << 8) + t;
            bool pred = (p < P) && (ubits[i] >= T);
            ull bal = __ballot(pred);
            if (pred) {
                int slot = run + __popcll(bal & lmask_lt);
                if (slot < 2 * KPRE)
                    arr[slot] = ((ull)ubits[i] << 32) | (unsigned int)(~p);
            }
            run += __popcll(bal);
        }
        __syncthreads();
        if (s_cnt <= 2 * KPRE || attempt == 1) { nval = min(s_cnt, 2 * KPRE); break; }
        // fallback: exact global search, lo invariant count>=256 holds at T
        unsigned int lo = T, hi = BITS_ONE1;
        int it = 0;
        while (hi - lo > 1u) {
            unsigned int mid = lo + ((hi - lo) >> 1);
            int cc = 0;
#pragma unroll
            for (int i = 0; i < NVMAX; ++i)
                cc += __popcll(__ballot(ubits[i] >= mid));
            if (lane == 0) wsum[it & 1][wid] = cc;
            __syncthreads();
            int totc = wsum[it & 1][0] + wsum[it & 1][1] + wsum[it & 1][2] + wsum[it & 1][3];
            if (totc >= KPRE) lo = mid; else hi = mid;
            ++it;
        }
        T = lo;
    }

    for (int e = t; e < 2 * KPRE; e += KPRE)
        if (e >= nval) arr[e] = 0ULL;
    __syncthreads();

    // D: 512-wide bitonic sort, 2 keys/thread (elem t and t+256), descending.
    // key = (bits<<32)|~idx => value desc, index asc (JAX tie-break).
    // LDS stages double-buffered: one barrier per stage.
    ull k0 = arr[t];
    ull k1 = arr[t + KPRE];
    {
        int lstage = 0;
#pragma unroll
        for (int kk = 2; kk <= 2 * KPRE; kk <<= 1) {
#pragma unroll
            for (int j = kk >> 1; j > 0; j >>= 1) {
                if (j == KPRE) {
                    ull mx = (k0 > k1) ? k0 : k1;
                    ull mn = (k0 > k1) ? k1 : k0;
                    k0 = mx; k1 = mn;
                } else if (j >= 64) {
                    ull* A = (lstage & 1) ? arr : arr2;
                    ++lstage;
                    A[t] = k0; A[t + KPRE] = k1;
                    __syncthreads();
                    ull o0 = A[t ^ j];
                    ull o1 = A[(t + KPRE) ^ j];
                    bool amLow = ((t & j) == 0);
                    bool d0 = ((t & kk) == 0);
                    bool d1 = (((t + KPRE) & kk) == 0);
                    k0 = (d0 == amLow) ? ((k0 > o0) ? k0 : o0) : ((k0 > o0) ? o0 : k0);
                    k1 = (d1 == amLow) ? ((k1 > o1) ? k1 : o1) : ((k1 > o1) ? o1 : k1);
                } else {
                    ull o0 = __shfl_xor(k0, j);
                    ull o1 = __shfl_xor(k1, j);
                    bool amLow = ((t & j) == 0);
                    bool d0 = ((t & kk) == 0);
                    bool d1 = (((t + KPRE) & kk) == 0);
                    k0 = (d0 == amLow) ? ((k0 > o0) ? k0 : o0) : ((k0 > o0) ? o0 : k0);
                    k1 = (d1 == amLow) ? ((k1 > o1) ? k1 : o1) : ((k1 > o1) ? o1 : k1);
                }
            }
        }
    }
    const ull key = k0;    // top-256 sorted descending

    // E: decode candidate t
    float v = __uint_as_float((unsigned int)(key >> 32));
    int idx = (int)(~(unsigned int)(key & 0xFFFFFFFFu));
    if (idx < 0 || idx >= P) { idx = 0; v = 0.f; }

    const float4 lv = *(const float4*)(loc + ((size_t)b * P + idx) * 4);
    const float4 pv = *(const float4*)(prior + (size_t)idx * 4);
    float cx = pv.x + (lv.x * VAR0) * pv.z;
    float cy = pv.y + (lv.y * VAR0) * pv.w;
    float w = pv.z * expf(lv.z * VAR1);
    float h = pv.w * expf(lv.w * VAR1);
    float x1 = cx - w * 0.5f;
    float y1 = cy - h * 0.5f;
    float x2 = x1 + w;
    float y2 = y1 + h;
    float myarea = fmaxf(x2 - x1, 0.f) * fmaxf(y2 - y1, 0.f);

    sbox[BSLOT(t)] = make_float4(x1, y1, x2, y2);
    sarea[BSLOT(t)] = myarea;
    __syncthreads();

    // F1: balanced mask build (640 (row,tile) pairs over 256 threads)
#pragma unroll
    for (int rep = 0; rep < 3; ++rep) {
        int pid = t + (rep << 8);
        if (pid < 640) {
            int r, w2;
            if (pid < 64)       { r = pid;                w2 = 0; }
            else if (pid < 192) { int q = pid - 64;  r = 64  + (q >> 1); w2 = q & 1; }
            else if (pid < 384) { int q = pid - 192; int q3 = q / 3; r = 128 + q3; w2 = q - 3 * q3; }
            else                { int q = pid - 384; r = 192 + (q >> 2); w2 = q & 3; }
            float4 rb = sbox[BSLOT(r)];
            float ra = sarea[BSLOT(r)];
            ull mm = 0ULL;
            for (int i = 0; i < 64; ++i) {
                int gg = (w2 << 6) + i;
                float4 gb = sbox[BSLOT(gg)];
                float lx = fmaxf(gb.x, rb.x), ly = fmaxf(gb.y, rb.y);
                float rx = fminf(gb.z, rb.z), ry = fminf(gb.w, rb.w);
                float iw = fmaxf(rx - lx, 0.f), ih = fmaxf(ry - ly, 0.f);
                float inter = iw * ih;
                float uni = sarea[BSLOT(gg)] + ra - inter;
                bool s = (inter / fmaxf(uni, 1e-9f)) > NMS_TH;
                mm |= ((ull)(s ? 1u : 0u)) << i;
            }
            smask[r][w2] = mm;
        }
    }
    __syncthreads();

    // F2: load row masks; resolve wave-serially, but only over lanes whose
    // suppression row is non-empty (todo) — suppressions are rare for random
    // boxes, so the 64-iter dependent-shfl chain shrinks to ~popc(todo).
    ull m0 = smask[t][0];
    ull m1 = (wid >= 1) ? smask[t][1] : 0ULL;
    ull m2 = (wid >= 2) ? smask[t][2] : 0ULL;
    ull m3 = (wid >= 3) ? smask[t][3] : 0ULL;
    if (wid == 0) m0 &= lmask_lt;
    else if (wid == 1) m1 &= lmask_lt;
    else if (wid == 2) m2 &= lmask_lt;
    else m3 &= lmask_lt;

    int alive = (v > CONF_TH) ? 1 : 0;
    ull mykept = 0ULL;
#pragma unroll
    for (int w2 = 0; w2 < 4; ++w2) {
        if (wid == w2) {
            if (w2 > 0 && (m0 & kept_mask[0])) alive = 0;
            if (w2 > 1 && (m1 & kept_mask[1])) alive = 0;
            if (w2 > 2 && (m2 & kept_mask[2])) alive = 0;
            ull mw = (w2 == 0) ? m0 : (w2 == 1) ? m1 : (w2 == 2) ? m2 : m3;
            ull validb = __ballot(alive != 0);
            ull todo = __ballot((mw & validb) != 0ULL) & validb;
            ull kept = validb & ~todo;
            while (todo) {
                int i = __builtin_ctzll(todo);
                ull row = __shfl(mw, i);
                if ((row & kept) == 0ULL) kept |= (1ULL << i);
                todo &= (todo - 1ULL);
            }
            mykept = kept;
            alive = (int)((kept >> lane) & 1ULL);
            if (lane == 0) kept_mask[w2] = kept;
        }
        __syncthreads();
    }

    // G: rank via popcounts, write kept rows + zero-fill
    int rank = 0;
#pragma unroll
    for (int w2 = 0; w2 < 4; ++w2)
        if (w2 < wid) rank += __popcll(kept_mask[w2]);
    rank += __popcll(mykept & lmask_lt);
    int total = 0;
#pragma unroll
    for (int w2 = 0; w2 < 4; ++w2) total += __popcll(kept_mask[w2]);

    float* orow = out + (size_t)pair * TOPK * 5;
    if (alive && rank < TOPK) {
        float* o = orow + rank * 5;
        o[0] = v; o[1] = x1; o[2] = y1; o[3] = x2; o[4] = y2;
    }
    if (t < TOPK && t >= total) {
        float* o = orow + t * 5;
        o[0] = 0.f; o[1] = 0.f; o[2] = 0.f; o[3] = 0.f; o[4] = 0.f;
    }
}

extern "C" void kernel_launch(void* const* d_in, const int* in_sizes, int n_in,
                              void* d_out, int out_size, void* d_ws, size_t ws_size,
                              hipStream_t stream) {
    const float* loc = (const float*)d_in[0];
    const float* conf = (const float*)d_in[1];
    const float* prior = (const float*)d_in[2];
    float* out = (float*)d_out;
    float2* norm = (float2*)d_ws;           // [B][P] (mx, sum) = 2.235 MB

    int P = in_sizes[2] / 4;                // 8732
    int B = in_sizes[0] / (4 * P);          // 32

    dim3 g1((P + 255) / 256, B);
    rownorm_kernel<<<g1, 256, 0, stream>>>(conf, norm, P);
    nms_topk_kernel<<<B * NFG, KPRE, 0, stream>>>(conf, norm, loc, prior, out, B, P);
}

// Round 3
// 135.268 us; speedup vs baseline: 1.0666x; 1.0666x over previous
//
#include <hip/hip_runtime.h>
#include <stdint.h>

typedef unsigned long long ull;

#define NUM_CLASSES 21
#define NFG 20
#define TOPK 200
#define KPRE 256
#define CONF_TH 0.01f
#define NMS_TH 0.45f
#define VAR0 0.1f
#define VAR1 0.2f
#define NVMAX 35                 // ceil(8732/256)
#define BITS_CONF 0x3C23D70Au    // __float_as_uint(0.01f)
#define BITS_ONE1 0x3F800001u    // just above 1.0f (softmax <= 1)
// skewed LDS slot: g, g+64, g+128, g+192 land in different banks
#define BSLOT(g) ((g) + ((g) >> 6))

// Kernel 1: softmax + transpose, register-row version. Each thread pulls its
// own 21-float row straight into registers (the wave's 21 gathers all land in
// one 5.25 KB span -> L1 absorbs; same line traffic as float4 staging but no
// input LDS, no staging barrier). LDS only for the 20 KB output transpose
// (-> higher occupancy than the 42 KB round-1 version). Math op order is
// identical to the verified kernel => bit-identical probs.
__global__ __launch_bounds__(256) void softmax_probs_kernel(
    const float* __restrict__ conf, float* __restrict__ probs, int P) {
    __shared__ __align__(16) float obuf[NFG * 256];          // 20480 B
    const int t = threadIdx.x;
    const int b = blockIdx.y;
    const int p0 = blockIdx.x << 8;
    const int cnt = min(256, P - p0);

    if (t < cnt) {
        const float* row = conf + ((size_t)b * P + p0 + t) * NUM_CLASSES;
        float x[NUM_CLASSES];
        float mx = row[0];
        x[0] = mx;
#pragma unroll
        for (int j = 1; j < NUM_CLASSES; ++j) { x[j] = row[j]; mx = fmaxf(mx, x[j]); }
        float s = 0.f;
#pragma unroll
        for (int j = 0; j < NUM_CLASSES; ++j) { x[j] = expf(x[j] - mx); s += x[j]; }
#pragma unroll
        for (int c = 1; c < NUM_CLASSES; ++c)
            obuf[(c - 1) * 256 + t] = x[c] / s;     // true div: match ref ulps
    }
    __syncthreads();

    float* dst = probs + ((size_t)b * NFG) * P + p0;
    if (cnt == 256) {
        // 20 classes x 64 float4; each wave stores one contiguous 1KB segment
        // per iteration. Row base (c*P floats) is 16B aligned (P%4==0).
#pragma unroll
        for (int k = 0; k < 5; ++k) {
            int e = (k << 8) + t;
            int c = e >> 6;
            int f = e & 63;
            float4 val = ((const float4*)obuf)[(c << 6) + f];
            *(float4*)(dst + (size_t)c * P + (f << 2)) = val;
        }
    } else {
        for (int e = t; e < NFG * cnt; e += 256) {
            int c = e / cnt;
            int f = e - c * cnt;
            dst[(size_t)c * P + f] = obuf[c * 256 + f];
        }
    }
}

// Kernel 2: one block per (b, fg_class). Phase A reads the transposed probs
// row COALESCED (the round-2 stride-84B conf gather was L2-request-bound:
// ~64 distinct lines per wave-load; 469 MB of L2 line traffic aggregate).
__global__ __launch_bounds__(KPRE) void nms_topk_kernel(
    const float* __restrict__ probs, const float* __restrict__ loc,
    const float* __restrict__ prior, float* __restrict__ out, int B, int P) {

    __shared__ ull arr[2 * KPRE];
    __shared__ ull arr2[2 * KPRE];              // double buffer for sort LDS stages
    __shared__ int wsum[2][4];
    __shared__ int s_cnt;
    __shared__ float4 sbox[KPRE + (KPRE >> 6)]; // skewed (BSLOT): no 4-way conflict
    __shared__ float sarea[KPRE + (KPRE >> 6)];
    __shared__ ull smask[KPRE][5];              // padded stride 40B: 2-way (free)
    __shared__ ull kept_mask[4];

    const int t = threadIdx.x;
    const int lane = t & 63;
    const int wid = t >> 6;
    const ull lmask_lt = (1ULL << lane) - 1ULL;

    // XCD-aware swizzle (bijective for B%8==0): all 20 classes of an image on
    // one XCD so phase-E loc/prior gathers reuse that XCD's L2.
    const int g = blockIdx.x;
    int b, c;
    if ((B & 7) == 0) {
        int k = g >> 3;
        b = ((k / NFG) << 3) + (g & 7);
        c = k - (k / NFG) * NFG;
    } else {
        b = g / NFG;
        c = g - (g / NFG) * NFG;
    }
    const int pair = b * NFG + c;
    const float* sp = probs + (size_t)pair * P;

    // A: scores into registers (coalesced dword loads)
    unsigned int ubits[NVMAX];
#pragma unroll
    for (int i = 0; i < NVMAX; ++i) {
        int p = (i << 8) + t;
        ubits[i] = (p < P) ? __float_as_uint(sp[p]) : 0u;
    }

    // B: WAVE-LOCAL binary search (no barriers, no shfl-reduce). Each wave
    // finds largest T_w with its own count >= 64 via ballot+popc (SALU).
    // Global T = min_w T_w  =>  count_global(>=T) >= 256 and T <= V256,
    // so {x >= T} is an exact superset of the global top-256.
    {
        unsigned int lo = BITS_CONF, hi = BITS_ONE1;
        while (hi - lo > 1u) {
            unsigned int mid = lo + ((hi - lo) >> 1);
            int cc = 0;
#pragma unroll
            for (int i = 0; i < NVMAX; ++i)
                cc += __popcll(__ballot(ubits[i] >= mid));
            if (cc >= KPRE / 4) lo = mid; else hi = mid;
        }
        if (lane == 0) wsum[0][wid] = (int)lo;
    }
    __syncthreads();
    unsigned int T = (unsigned int)min(min(wsum[0][0], wsum[0][1]),
                                       min(wsum[0][2], wsum[0][3]));

    // C: ballot-compaction gather (cap 512) + exact-search fallback if the
    // wave-local threshold over-collects (>512: statistically never).
    int nval;
    for (int attempt = 0;; ++attempt) {
        if (t == 0) s_cnt = 0;
        __syncthreads();
        int wtot = 0;
#pragma unroll
        for (int i = 0; i < NVMAX; ++i) {
            int p = (i << 8) + t;
            bool pred = (p < P) && (ubits[i] >= T);
            wtot += __popcll(__ballot(pred));
        }
        int wbase = 0;
        if (lane == 0) wbase = atomicAdd(&s_cnt, wtot);
        wbase = __shfl(wbase, 0);
        int run = wbase;
#pragma unroll
        for (int i = 0; i < NVMAX; ++i) {
            int p = (i << 8) + t;
            bool pred = (p < P) && (ubits[i] >= T);
            ull bal = __ballot(pred);
            if (pred) {
                int slot = run + __popcll(bal & lmask_lt);
                if (slot < 2 * KPRE)
                    arr[slot] = ((ull)ubits[i] << 32) | (unsigned int)(~p);
            }
            run += __popcll(bal);
        }
        __syncthreads();
        if (s_cnt <= 2 * KPRE || attempt == 1) { nval = min(s_cnt, 2 * KPRE); break; }
        // fallback: exact global search, lo invariant count>=256 holds at T
        unsigned int lo = T, hi = BITS_ONE1;
        int it = 0;
        while (hi - lo > 1u) {
            unsigned int mid = lo + ((hi - lo) >> 1);
            int cc = 0;
#pragma unroll
            for (int i = 0; i < NVMAX; ++i)
                cc += __popcll(__ballot(ubits[i] >= mid));
            if (lane == 0) wsum[it & 1][wid] = cc;
            __syncthreads();
            int totc = wsum[it & 1][0] + wsum[it & 1][1] + wsum[it & 1][2] + wsum[it & 1][3];
            if (totc >= KPRE) lo = mid; else hi = mid;
            ++it;
        }
        T = lo;
    }

    for (int e = t; e < 2 * KPRE; e += KPRE)
        if (e >= nval) arr[e] = 0ULL;
    __syncthreads();

    // D: 512-wide bitonic sort, 2 keys/thread (elem t and t+256), descending.
    // key = (bits<<32)|~idx => value desc, index asc (JAX tie-break).
    // LDS stages double-buffered: one barrier per stage.
    ull k0 = arr[t];
    ull k1 = arr[t + KPRE];
    {
        int lstage = 0;
#pragma unroll
        for (int kk = 2; kk <= 2 * KPRE; kk <<= 1) {
#pragma unroll
            for (int j = kk >> 1; j > 0; j >>= 1) {
                if (j == KPRE) {
                    ull mx = (k0 > k1) ? k0 : k1;
                    ull mn = (k0 > k1) ? k1 : k0;
                    k0 = mx; k1 = mn;
                } else if (j >= 64) {
                    ull* A = (lstage & 1) ? arr : arr2;
                    ++lstage;
                    A[t] = k0; A[t + KPRE] = k1;
                    __syncthreads();
                    ull o0 = A[t ^ j];
                    ull o1 = A[(t + KPRE) ^ j];
                    bool amLow = ((t & j) == 0);
                    bool d0 = ((t & kk) == 0);
                    bool d1 = (((t + KPRE) & kk) == 0);
                    k0 = (d0 == amLow) ? ((k0 > o0) ? k0 : o0) : ((k0 > o0) ? o0 : k0);
                    k1 = (d1 == amLow) ? ((k1 > o1) ? k1 : o1) : ((k1 > o1) ? o1 : k1);
                } else {
                    ull o0 = __shfl_xor(k0, j);
                    ull o1 = __shfl_xor(k1, j);
                    bool amLow = ((t & j) == 0);
                    bool d0 = ((t & kk) == 0);
                    bool d1 = (((t + KPRE) & kk) == 0);
                    k0 = (d0 == amLow) ? ((k0 > o0) ? k0 : o0) : ((k0 > o0) ? o0 : k0);
                    k1 = (d1 == amLow) ? ((k1 > o1) ? k1 : o1) : ((k1 > o1) ? o1 : k1);
                }
            }
        }
    }
    const ull key = k0;    // top-256 sorted descending

    // E: decode candidate t
    float v = __uint_as_float((unsigned int)(key >> 32));
    int idx = (int)(~(unsigned int)(key & 0xFFFFFFFFu));
    if (idx < 0 || idx >= P) { idx = 0; v = 0.f; }

    const float4 lv = *(const float4*)(loc + ((size_t)b * P + idx) * 4);
    const float4 pv = *(const float4*)(prior + (size_t)idx * 4);
    float cx = pv.x + (lv.x * VAR0) * pv.z;
    float cy = pv.y + (lv.y * VAR0) * pv.w;
    float w = pv.z * expf(lv.z * VAR1);
    float h = pv.w * expf(lv.w * VAR1);
    float x1 = cx - w * 0.5f;
    float y1 = cy - h * 0.5f;
    float x2 = x1 + w;
    float y2 = y1 + h;
    float myarea = fmaxf(x2 - x1, 0.f) * fmaxf(y2 - y1, 0.f);

    sbox[BSLOT(t)] = make_float4(x1, y1, x2, y2);
    sarea[BSLOT(t)] = myarea;
    __syncthreads();

    // F1: balanced mask build (640 (row,tile) pairs over 256 threads)
#pragma unroll
    for (int rep = 0; rep < 3; ++rep) {
        int pid = t + (rep << 8);
        if (pid < 640) {
            int r, w2;
            if (pid < 64)       { r = pid;                w2 = 0; }
            else if (pid < 192) { int q = pid - 64;  r = 64  + (q >> 1); w2 = q & 1; }
            else if (pid < 384) { int q = pid - 192; int q3 = q / 3; r = 128 + q3; w2 = q - 3 * q3; }
            else                { int q = pid - 384; r = 192 + (q >> 2); w2 = q & 3; }
            float4 rb = sbox[BSLOT(r)];
            float ra = sarea[BSLOT(r)];
            ull mm = 0ULL;
            for (int i = 0; i < 64; ++i) {
                int gg = (w2 << 6) + i;
                float4 gb = sbox[BSLOT(gg)];
                float lx = fmaxf(gb.x, rb.x), ly = fmaxf(gb.y, rb.y);
                float rx = fminf(gb.z, rb.z), ry = fminf(gb.w, rb.w);
                float iw = fmaxf(rx - lx, 0.f), ih = fmaxf(ry - ly, 0.f);
                float inter = iw * ih;
                float uni = sarea[BSLOT(gg)] + ra - inter;
                bool s = (inter / fmaxf(uni, 1e-9f)) > NMS_TH;
                mm |= ((ull)(s ? 1u : 0u)) << i;
            }
            smask[r][w2] = mm;
        }
    }
    __syncthreads();

    // F2: load row masks; resolve wave-serially, but only over lanes whose
    // suppression row is non-empty (todo) — suppressions are rare for random
    // boxes, so the 64-iter dependent-shfl chain shrinks to ~popc(todo).
    ull m0 = smask[t][0];
    ull m1 = (wid >= 1) ? smask[t][1] : 0ULL;
    ull m2 = (wid >= 2) ? smask[t][2] : 0ULL;
    ull m3 = (wid >= 3) ? smask[t][3] : 0ULL;
    if (wid == 0) m0 &= lmask_lt;
    else if (wid == 1) m1 &= lmask_lt;
    else if (wid == 2) m2 &= lmask_lt;
    else m3 &= lmask_lt;

    int alive = (v > CONF_TH) ? 1 : 0;
    ull mykept = 0ULL;
#pragma unroll
    for (int w2 = 0; w2 < 4; ++w2) {
        if (wid == w2) {
            if (w2 > 0 && (m0 & kept_mask[0])) alive = 0;
            if (w2 > 1 && (m1 & kept_mask[1])) alive = 0;
            if (w2 > 2 && (m2 & kept_mask[2])) alive = 0;
            ull mw = (w2 == 0) ? m0 : (w2 == 1) ? m1 : (w2 == 2) ? m2 : m3;
            ull validb = __ballot(alive != 0);
            ull todo = __ballot((mw & validb) != 0ULL) & validb;
            ull kept = validb & ~todo;
            while (todo) {
                int i = __builtin_ctzll(todo);
                ull row = __shfl(mw, i);
                if ((row & kept) == 0ULL) kept |= (1ULL << i);
                todo &= (todo - 1ULL);
            }
            mykept = kept;
            alive = (int)((kept >> lane) & 1ULL);
            if (lane == 0) kept_mask[w2] = kept;
        }
        __syncthreads();
    }

    // G: rank via popcounts, write kept rows + zero-fill
    int rank = 0;
#pragma unroll
    for (int w2 = 0; w2 < 4; ++w2)
        if (w2 < wid) rank += __popcll(kept_mask[w2]);
    rank += __popcll(mykept & lmask_lt);
    int total = 0;
#pragma unroll
    for (int w2 = 0; w2 < 4; ++w2) total += __popcll(kept_mask[w2]);

    float* orow = out + (size_t)pair * TOPK * 5;
    if (alive && rank < TOPK) {
        float* o = orow + rank * 5;
        o[0] = v; o[1] = x1; o[2] = y1; o[3] = x2; o[4] = y2;
    }
    if (t < TOPK && t >= total) {
        float* o = orow + t * 5;
        o[0] = 0.f; o[1] = 0.f; o[2] = 0.f; o[3] = 0.f; o[4] = 0.f;
    }
}

extern "C" void kernel_launch(void* const* d_in, const int* in_sizes, int n_in,
                              void* d_out, int out_size, void* d_ws, size_t ws_size,
                              hipStream_t stream) {
    const float* loc = (const float*)d_in[0];
    const float* conf = (const float*)d_in[1];
    const float* prior = (const float*)d_in[2];
    float* out = (float*)d_out;
    float* probs = (float*)d_ws;            // [B][NFG][P] floats = 22.35 MB

    int P = in_sizes[2] / 4;                // 8732
    int B = in_sizes[0] / (4 * P);          // 32

    dim3 g1((P + 255) / 256, B);
    softmax_probs_kernel<<<g1, 256, 0, stream>>>(conf, probs, P);
    nms_topk_kernel<<<B * NFG, KPRE, 0, stream>>>(probs, loc, prior, out, B, P);
}